// Round 1
// baseline (58.934 us; speedup 1.0000x reference)
//
#include <hip/hip_runtime.h>

// QuantumParity analytic form:
//   The reference builds a product state |psi> = ⊗_q [cos(x_q/2), sin(x_q/2)],
//   applies a CNOT ladder (a permutation h of basis states), squares to probs,
//   and projects onto Z_j and Z_i Z_j features.
//   Pulling h into the features: bit_j(h^{-1}(u)) = XOR of bits 0..j of u, so
//     <Z_j>      -> prod_{q=0..j}   cos(x_q)
//     <Z_i Z_j>  -> prod_{q=i+1..j} cos(x_q)
//   (cos^2 - sin^2 = cos, and overlapping Z factors square away).
//   Output: y_o = b_o + sum_k W[o,k] * F_k,  o in {0,1}.

#define NQ 8
#define NFEAT 36  // 8 singles + 28 pairs

__global__ __launch_bounds__(256) void quantum_parity_kernel(
    const float* __restrict__ x,     // (B, 8)
    const float* __restrict__ W,     // (2, 36)
    const float* __restrict__ bias,  // (2,)
    float* __restrict__ out,         // (B, 2)
    int B) {
  int b = blockIdx.x * blockDim.x + threadIdx.x;
  if (b >= B) return;

  // Coalesced: each lane reads its 32 contiguous bytes as two float4.
  const float4* xv = (const float4*)(x + (size_t)b * NQ);
  float4 a0 = xv[0];
  float4 a1 = xv[1];

  float c[NQ];
  c[0] = cosf(a0.x);
  c[1] = cosf(a0.y);
  c[2] = cosf(a0.z);
  c[3] = cosf(a0.w);
  c[4] = cosf(a1.x);
  c[5] = cosf(a1.y);
  c[6] = cosf(a1.z);
  c[7] = cosf(a1.w);

  float F[NFEAT];
  // Singles: prefix products P_j = c_0 * ... * c_j
  float p = 1.0f;
#pragma unroll
  for (int j = 0; j < NQ; ++j) {
    p *= c[j];
    F[j] = p;
  }
  // Pairs (i<j): product c_{i+1} .. c_j, in i-major order matching S columns.
  int k = NQ;
#pragma unroll
  for (int i = 0; i < NQ; ++i) {
    float r = 1.0f;
#pragma unroll
    for (int j = i + 1; j < NQ; ++j) {
      r *= c[j];
      F[k++] = r;
    }
  }

  // W is uniform across lanes -> compiler emits scalar loads; fully unrolled.
  float y0 = bias[0];
  float y1 = bias[1];
#pragma unroll
  for (int t = 0; t < NFEAT; ++t) {
    y0 = fmaf(W[t], F[t], y0);
    y1 = fmaf(W[NFEAT + t], F[t], y1);
  }

  ((float2*)out)[b] = make_float2(y0, y1);
}

extern "C" void kernel_launch(void* const* d_in, const int* in_sizes, int n_in,
                              void* d_out, int out_size, void* d_ws, size_t ws_size,
                              hipStream_t stream) {
  const float* x = (const float*)d_in[0];
  const float* W = (const float*)d_in[1];
  const float* bias = (const float*)d_in[2];
  float* out = (float*)d_out;

  int B = in_sizes[0] / NQ;  // 131072
  int block = 256;
  int grid = (B + block - 1) / block;
  quantum_parity_kernel<<<grid, block, 0, stream>>>(x, W, bias, out, B);
}

// Round 2
// 58.332 us; speedup vs baseline: 1.0103x; 1.0103x over previous
//
#include <hip/hip_runtime.h>

// QuantumParity analytic form:
//   |psi> = ⊗_q [cos(x_q/2), sin(x_q/2)], CNOT ladder = basis permutation h,
//   probs are a product distribution. Pulling h into the Z/ZZ features:
//     <Z_j>     -> prod_{q=0..j}   cos(x_q)
//     <Z_i Z_j> -> prod_{q=i+1..j} cos(x_q)
//   y_o = b_o + sum_k W[o,k] * F_k.
//
// x in [0, pi] -> x/(2pi) in [0, 0.5]: hardware v_cos_f32 (revolutions input)
// needs NO range reduction. cos(x) = __builtin_amdgcn_cosf(x * 1/(2pi)).

#define NQ 8
#define NFEAT 36  // 8 singles + 28 pairs
#define INV_2PI 0.15915494309189535f

__device__ __forceinline__ float2 sample_out(float4 a0, float4 a1,
                                             const float* __restrict__ W,
                                             float b0, float b1) {
  float c[NQ];
  c[0] = __builtin_amdgcn_cosf(a0.x * INV_2PI);
  c[1] = __builtin_amdgcn_cosf(a0.y * INV_2PI);
  c[2] = __builtin_amdgcn_cosf(a0.z * INV_2PI);
  c[3] = __builtin_amdgcn_cosf(a0.w * INV_2PI);
  c[4] = __builtin_amdgcn_cosf(a1.x * INV_2PI);
  c[5] = __builtin_amdgcn_cosf(a1.y * INV_2PI);
  c[6] = __builtin_amdgcn_cosf(a1.z * INV_2PI);
  c[7] = __builtin_amdgcn_cosf(a1.w * INV_2PI);

  float F[NFEAT];
  float p = 1.0f;
#pragma unroll
  for (int j = 0; j < NQ; ++j) {
    p *= c[j];
    F[j] = p;
  }
  int k = NQ;
#pragma unroll
  for (int i = 0; i < NQ; ++i) {
    float r = 1.0f;
#pragma unroll
    for (int j = i + 1; j < NQ; ++j) {
      r *= c[j];
      F[k++] = r;
    }
  }

  float y0 = b0, y1 = b1;
#pragma unroll
  for (int t = 0; t < NFEAT; ++t) {
    y0 = fmaf(W[t], F[t], y0);
    y1 = fmaf(W[NFEAT + t], F[t], y1);
  }
  return make_float2(y0, y1);
}

__global__ __launch_bounds__(256) void quantum_parity_kernel(
    const float4* __restrict__ x4,   // (B, 8) viewed as (2B) float4
    const float* __restrict__ W,     // (2, 36)
    const float* __restrict__ bias,  // (2,)
    float4* __restrict__ out4,       // (B, 2) viewed as (B/2) float4
    int Bhalf) {                     // B/2 threads, 2 samples each
  int t = blockIdx.x * blockDim.x + threadIdx.x;
  if (t >= Bhalf) return;

  float b0 = bias[0], b1 = bias[1];

  // Sample 2t and 2t+1: four consecutive float4 loads (64 B/lane).
  float4 a0 = x4[4 * t + 0];
  float4 a1 = x4[4 * t + 1];
  float4 a2 = x4[4 * t + 2];
  float4 a3 = x4[4 * t + 3];

  float2 r0 = sample_out(a0, a1, W, b0, b1);
  float2 r1 = sample_out(a2, a3, W, b0, b1);

  out4[t] = make_float4(r0.x, r0.y, r1.x, r1.y);
}

extern "C" void kernel_launch(void* const* d_in, const int* in_sizes, int n_in,
                              void* d_out, int out_size, void* d_ws, size_t ws_size,
                              hipStream_t stream) {
  const float* x = (const float*)d_in[0];
  const float* W = (const float*)d_in[1];
  const float* bias = (const float*)d_in[2];
  float* out = (float*)d_out;

  int B = in_sizes[0] / NQ;  // 131072
  int Bhalf = B / 2;
  int block = 256;
  int grid = (Bhalf + block - 1) / block;
  quantum_parity_kernel<<<grid, block, 0, stream>>>(
      (const float4*)x, W, bias, (float4*)out, Bhalf);
}